// Round 20
// baseline (229.120 us; speedup 1.0000x reference)
//
#include <hip/hip_runtime.h>
#include <hip/hip_bf16.h>

typedef __attribute__((ext_vector_type(8))) short bf16x8;
typedef __attribute__((ext_vector_type(4))) float f32x4;
typedef __attribute__((ext_vector_type(4))) unsigned short us4;

#define DEV __device__ __forceinline__

constexpr int Bc = 8, Tc = 1024, HIDc = 2048, Hc = 16, Dc = 128;
constexpr int ROWSc = Bc * Tc;  // 8192

DEV unsigned short f2bfb(float x) {
  union { float f; unsigned u; } v; v.f = x;
  unsigned r = v.u + 0x7fffu + ((v.u >> 16) & 1u);  // round-to-nearest-even
  return (unsigned short)(r >> 16);
}
DEV float bfb2f(unsigned short b) {
  union { unsigned u; float f; } v; v.u = ((unsigned)b) << 16; return v.f;
}
DEV float fexp2(float x) { return __builtin_amdgcn_exp2f(x); }  // native v_exp_f32
DEV unsigned pkbf(float lo, float hi) {  // 2 bf16 (round-half-up) packed in u32
  union { float f; unsigned u; } a, b; a.f = lo; b.f = hi;
  return ((b.u + 0x8000u) & 0xffff0000u) | ((a.u + 0x8000u) >> 16);
}

// async global->LDS, 16B per lane; LDS dest MUST be linear in lane order
// (wave-uniform base + lane*16) — rule 21 / m104.
DEV void gload16(const void* g, void* l) {
  __builtin_amdgcn_global_load_lds(
      (const __attribute__((address_space(1))) unsigned int*)g,
      (__attribute__((address_space(3))) unsigned int*)l, 16, 0, 0);
}

// 32x32 fp32->bf16 transpose tile helper (tile = 32x33 floats in LDS)
DEV void tr32(const float* __restrict__ in, unsigned short* __restrict__ out,
              int R, int C, int bx, int by, float (*tile)[33], int tx, int ty) {
  int r0 = by * 32, c0 = bx * 32;
#pragma unroll
  for (int i = 0; i < 4; i++)
    tile[ty + i * 8][tx] = in[(size_t)(r0 + ty + i * 8) * C + c0 + tx];
  __syncthreads();
#pragma unroll
  for (int i = 0; i < 4; i++) {
    int rr = ty + i * 8;
    out[(size_t)(c0 + rr) * R + r0 + tx] = f2bfb(tile[tx][rr]);
  }
}

// ---------------- prep1: small transposes + blend + zero (1424 blocks) ----------------

__global__ __launch_bounds__(256) void k_prep1(
    const float* __restrict__ Wq_a, const float* __restrict__ Wkv_a,
    const float* __restrict__ Wq_b, const float* __restrict__ Wkv_b,
    const float* __restrict__ cg, const float* __restrict__ sg,
    const float* __restrict__ cl, const float* __restrict__ sl,
    const float* __restrict__ gl,
    unsigned short* __restrict__ W1t, unsigned short* __restrict__ Wqbt,
    unsigned short* __restrict__ Wkbt,
    float* __restrict__ cosb, float* __restrict__ sinb) {
  __shared__ float tile[32][33];
  int bid = blockIdx.x;
  int tid = threadIdx.x;
  int tx = tid & 31, ty = tid >> 5;
  if (bid < 256) {
    tr32(Wq_a, W1t, 2048, 128, bid & 3, bid >> 2, tile, tx, ty);
  } else if (bid < 384) {
    int i = bid - 256;
    tr32(Wkv_a, W1t + (size_t)128 * 2048, 2048, 64, i & 1, i >> 1, tile, tx, ty);
  } else if (bid < 640) {
    int i = bid - 384;
    tr32(Wq_b, Wqbt, 128, 2048, i & 63, i >> 6, tile, tx, ty);
  } else if (bid < 656) {
    int i = bid - 640;
    tr32(Wkv_b, Wkbt, 64, 256, i & 7, i >> 3, tile, tx, ty);
  } else if (bid < 912) {
    int u = (bid - 656) * 256 + tid;  // < 65536
    float a = 1.0f / (1.0f + __expf(-gl[0]));
    cosb[u] = cg[u] * a + cl[u] * (1.0f - a);
    sinb[u] = sg[u] * a + sl[u] * (1.0f - a);
  } else {
    int i = (bid - 912) * 256 + tid;  // < 131072
    W1t[(size_t)192 * 2048 + i] = 0;
  }
}

// ---------------- g1wo: GEMM1 (split-K2 dbuf) + Wo transpose backfill ----------------

__global__ __launch_bounds__(256) void k_g1wo(const float* __restrict__ A,
                                              const unsigned short* __restrict__ Bt,
                                              float* __restrict__ C0,
                                              float* __restrict__ C1,
                                              const float* __restrict__ Wo,
                                              unsigned short* __restrict__ Wot) {
  constexpr int K = 2048, N = 256, KH = 1024, NT = KH / 32;
  __shared__ __align__(16) unsigned short smem[12288];  // 24 KB union
  int bid = blockIdx.x;
  int tid = threadIdx.x;

  if (bid >= 512) {  // ---- Wo transpose path
    int i = bid - 512;
    float (*tile)[33] = (float(*)[33])smem;
    tr32(Wo, Wot, 2048, 2048, i & 63, i >> 6, tile, tid & 31, tid >> 5);
    return;
  }

  // ---- gemm1 path
  unsigned short* AlsF = smem;          // [2][2048]
  unsigned short* BlsF = smem + 4096;   // [2][4096]
  int wg = (bid & 7) * 64 + (bid >> 3);
  int ksl = wg & 1;
  int nti = (wg >> 1) & 1;
  int mti = wg >> 2;
  int m0 = mti * 64, n0 = nti * 128, k0 = ksl * KH;
  float* C = ksl ? C1 : C0;
  int lane = tid & 63, wc = tid >> 6;
  int ar = tid >> 2, akc = (tid & 3) * 8;
  const float* Ag = A + (size_t)(m0 + ar) * K + k0 + akc;
  const unsigned short* Bg0 = Bt + (size_t)(n0 + ar) * K + k0 + akc;
  const unsigned short* Bg1 = Bt + (size_t)(n0 + 64 + ar) * K + k0 + akc;
  f32x4 acc[4][2];
  f32x4 zz = {0.f, 0.f, 0.f, 0.f};
#pragma unroll
  for (int m = 0; m < 4; m++)
#pragma unroll
    for (int n = 0; n < 2; n++) acc[m][n] = zz;
  int fr = lane & 15, fk = (lane >> 4) * 8;

  float4 a0 = *(const float4*)(Ag);
  float4 a1 = *(const float4*)(Ag + 4);
  gload16(Bg0, &BlsF[tid * 8]);
  gload16(Bg1, &BlsF[2048 + tid * 8]);
  {
    us4 c0v = { f2bfb(a0.x), f2bfb(a0.y), f2bfb(a0.z), f2bfb(a0.w) };
    us4 c1v = { f2bfb(a1.x), f2bfb(a1.y), f2bfb(a1.z), f2bfb(a1.w) };
    *(us4*)&AlsF[ar * 32 + akc] = c0v;
    *(us4*)&AlsF[ar * 32 + akc + 4] = c1v;
  }
  a0 = *(const float4*)(Ag + 32);
  a1 = *(const float4*)(Ag + 36);
  __syncthreads();  // buf0 staged

  for (int t = 0; t < NT; t++) {
    int cur = t & 1, nxt = cur ^ 1;
    if (t + 1 < NT) {
      gload16(Bg0 + (t + 1) * 32, &BlsF[nxt * 4096 + tid * 8]);
      gload16(Bg1 + (t + 1) * 32, &BlsF[nxt * 4096 + 2048 + tid * 8]);
    }
    bf16x8 af[4], bfv[2];
#pragma unroll
    for (int i = 0; i < 4; i++)
      af[i] = *(const bf16x8*)&AlsF[cur * 2048 + (i * 16 + fr) * 32 + fk];
#pragma unroll
    for (int i = 0; i < 2; i++)
      bfv[i] = *(const bf16x8*)&BlsF[cur * 4096 + (wc * 32 + i * 16 + fr) * 32 + fk];
    __builtin_amdgcn_s_setprio(1);
#pragma unroll
    for (int m = 0; m < 4; m++)
#pragma unroll
      for (int n = 0; n < 2; n++)
        acc[m][n] = __builtin_amdgcn_mfma_f32_16x16x32_bf16(af[m], bfv[n], acc[m][n], 0, 0, 0);
    __builtin_amdgcn_s_setprio(0);
    if (t + 1 < NT) {
      us4 d0 = { f2bfb(a0.x), f2bfb(a0.y), f2bfb(a0.z), f2bfb(a0.w) };
      us4 d1 = { f2bfb(a1.x), f2bfb(a1.y), f2bfb(a1.z), f2bfb(a1.w) };
      *(us4*)&AlsF[nxt * 2048 + ar * 32 + akc] = d0;
      *(us4*)&AlsF[nxt * 2048 + ar * 32 + akc + 4] = d1;
    }
    if (t + 2 < NT) {
      a0 = *(const float4*)(Ag + (t + 2) * 32);
      a1 = *(const float4*)(Ag + (t + 2) * 32 + 4);
    }
    __syncthreads();
  }
  int gg = lane >> 4;
#pragma unroll
  for (int m = 0; m < 4; m++)
#pragma unroll
    for (int n = 0; n < 2; n++)
#pragma unroll
      for (int r = 0; r < 4; r++) {
        size_t row = (size_t)m0 + m * 16 + gg * 4 + r;
        size_t col = (size_t)n0 + wc * 32 + n * 16 + fr;
        C[row * N + col] = acc[m][n][r];
      }
}

// ---------------- GEMM3: 256x256 tile, BK=64 (2 K-slices), counted-vmcnt ----------------

__global__ __launch_bounds__(512, 2) void k_gemm3(const unsigned short* __restrict__ A,
                                                  const unsigned short* __restrict__ Bt,
                                                  float* __restrict__ C) {
  constexpr int K = 2048, N = 2048, NT = K / 64;
  __shared__ __align__(16) unsigned short Als[2][2][8192];
  __shared__ __align__(16) unsigned short Bls[2][2][8192];
  int lin = blockIdx.x;
  int wg = (lin & 7) * 32 + (lin >> 3);   // XCD-contiguous
  int m0 = (wg >> 3) * 256, n0 = (wg & 7) * 256;
  int tid = threadIdx.x, lane = tid & 63, wave = tid >> 6;
  int wm = wave >> 2, wn = wave & 3;
  int g = lane >> 4, c = lane & 15;

  int rb = tid >> 2;
  int sch = (tid & 3) ^ ((tid >> 3) & 3);
  const unsigned short* Ag = A + (size_t)(m0 + rb) * K + sch * 8;
  const unsigned short* Bg = Bt + (size_t)(n0 + rb) * K + sch * 8;
  const int gsw = (g ^ ((c >> 1) & 3)) * 8;

  f32x4 acc[8][4];
  f32x4 zz = {0.f, 0.f, 0.f, 0.f};
#pragma unroll
  for (int mi = 0; mi < 8; mi++)
#pragma unroll
    for (int ni = 0; ni < 4; ni++) acc[mi][ni] = zz;

#pragma unroll
  for (int sl = 0; sl < 2; sl++) {
    gload16(Ag + sl * 32, &Als[0][sl][tid * 8]);
    gload16(Ag + (size_t)128 * K + sl * 32, &Als[0][sl][4096 + tid * 8]);
    gload16(Bg + sl * 32, &Bls[0][sl][tid * 8]);
    gload16(Bg + (size_t)128 * K + sl * 32, &Bls[0][sl][4096 + tid * 8]);
  }

  for (int t = 0; t < NT; ++t) {
    int buf = t & 1, nb = buf ^ 1;
    bool nl = (t + 1 < NT);
    int nkt = (t + 1) * 64;
#pragma unroll
    for (int sl = 0; sl < 2; sl++) {
      if (sl == 0 || nl) {
        asm volatile("s_waitcnt vmcnt(4)" ::: "memory");
      } else {
        asm volatile("s_waitcnt vmcnt(0)" ::: "memory");
      }
      __builtin_amdgcn_sched_barrier(0);
      __builtin_amdgcn_s_barrier();
      __builtin_amdgcn_sched_barrier(0);
      const unsigned short* As_ = &Als[buf][sl][0];
      const unsigned short* Bs_ = &Bls[buf][sl][0];
      bf16x8 af[8], bfv[4];
#pragma unroll
      for (int mi = 0; mi < 8; mi++)
        af[mi] = *(const bf16x8*)&As_[(wm * 128 + mi * 16 + c) * 32 + gsw];
#pragma unroll
      for (int ni = 0; ni < 4; ni++)
        bfv[ni] = *(const bf16x8*)&Bs_[(wn * 64 + ni * 16 + c) * 32 + gsw];
      if (nl) {
        gload16(Ag + nkt + sl * 32, &Als[nb][sl][tid * 8]);
        gload16(Ag + (size_t)128 * K + nkt + sl * 32, &Als[nb][sl][4096 + tid * 8]);
      }
      __builtin_amdgcn_s_setprio(1);
#pragma unroll
      for (int mi = 0; mi < 8; mi++) {
        acc[mi][0] = __builtin_amdgcn_mfma_f32_16x16x32_bf16(af[mi], bfv[0], acc[mi][0], 0, 0, 0);
        acc[mi][1] = __builtin_amdgcn_mfma_f32_16x16x32_bf16(af[mi], bfv[1], acc[mi][1], 0, 0, 0);
      }
      __builtin_amdgcn_s_setprio(0);
      if (nl) {
        gload16(Bg + nkt + sl * 32, &Bls[nb][sl][tid * 8]);
        gload16(Bg + (size_t)128 * K + nkt + sl * 32, &Bls[nb][sl][4096 + tid * 8]);
      }
      __builtin_amdgcn_s_setprio(1);
#pragma unroll
      for (int mi = 0; mi < 8; mi++) {
        acc[mi][2] = __builtin_amdgcn_mfma_f32_16x16x32_bf16(af[mi], bfv[2], acc[mi][2], 0, 0, 0);
        acc[mi][3] = __builtin_amdgcn_mfma_f32_16x16x32_bf16(af[mi], bfv[3], acc[mi][3], 0, 0, 0);
      }
      __builtin_amdgcn_s_setprio(0);
    }
  }

#pragma unroll
  for (int mi = 0; mi < 8; mi++)
#pragma unroll
    for (int ni = 0; ni < 4; ni++)
#pragma unroll
      for (int r = 0; r < 4; r++) {
        size_t row = (size_t)m0 + wm * 128 + mi * 16 + g * 4 + r;
        size_t col = (size_t)n0 + wn * 64 + ni * 16 + c;
        C[row * N + col] = acc[mi][ni][r];
      }
}

// ---------------- g2: GEMM2a+RoPE-Q (blocks 0..1023) + GEMM2b+RoPE-K/V (1024..1151) ----------------

__global__ __launch_bounds__(256) void k_g2(const unsigned short* __restrict__ Aq,
                                            const unsigned short* __restrict__ Btq,
                                            const float* __restrict__ bqb,
                                            const unsigned short* __restrict__ Akv,
                                            const unsigned short* __restrict__ Btkv,
                                            const float* __restrict__ bkvb,
                                            const float* __restrict__ cosb,
                                            const float* __restrict__ sinb,
                                            const float* __restrict__ nl,
                                            unsigned short* __restrict__ Qf,
                                            unsigned short* __restrict__ Kf,
                                            unsigned short* __restrict__ Vt) {
  __shared__ __align__(16) unsigned short smem[36864];  // 72 KB union
  int bid = blockIdx.x;
  int tid = threadIdx.x;
  int lane = tid & 63;

  if (bid >= 1024) {  // ---- gemm2kv path
    unsigned short* As2 = smem;           // [64*64]
    unsigned short* Bs2 = smem + 4096;    // [256*64]
    unsigned short* KVt = smem + 20480;   // [64*256]
    int m0 = (bid - 1024) * 64;
    int b = m0 >> 10, t0 = m0 & 1023;
    int wc = tid >> 6;
    int fr = lane & 15, gg = lane >> 4;
#pragma unroll
    for (int p = 0; p < 2; p++) {
      int slot = p * 256 + tid;
      int row = slot >> 3, chpos = slot & 7;
      gload16(Akv + (size_t)(m0 + row) * 64 + ((chpos ^ (row & 7)) << 3),
              &As2[slot * 8]);
    }
#pragma unroll
    for (int p = 0; p < 8; p++) {
      int slot = p * 256 + tid;
      int row = slot >> 3, chpos = slot & 7;
      gload16(Btkv + (size_t)row * 64 + ((chpos ^ (row & 7)) << 3),
              &Bs2[slot * 8]);
    }
    __syncthreads();
    f32x4 acc[4][4];
    f32x4 zz = {0.f, 0.f, 0.f, 0.f};
#pragma unroll
    for (int m = 0; m < 4; m++)
#pragma unroll
      for (int n = 0; n < 4; n++) acc[m][n] = zz;
#pragma unroll
    for (int ks = 0; ks < 2; ks++) {
      bf16x8 af[4], bfv[4];
#pragma unroll
      for (int m = 0; m < 4; m++) {
        int row = m * 16 + fr;
        af[m] = *(const bf16x8*)&As2[row * 64 + (((ks * 4 + gg) ^ (row & 7)) << 3)];
      }
#pragma unroll
      for (int n = 0; n < 4; n++) {
        int row = wc * 64 + n * 16 + fr;
        bfv[n] = *(const bf16x8*)&Bs2[row * 64 + (((ks * 4 + gg) ^ (row & 7)) << 3)];
      }
#pragma unroll
      for (int m = 0; m < 4; m++)
#pragma unroll
        for (int n = 0; n < 4; n++)
          acc[m][n] = __builtin_amdgcn_mfma_f32_16x16x32_bf16(af[m], bfv[n], acc[m][n], 0, 0, 0);
    }
#pragma unroll
    for (int n = 0; n < 4; n++) {
      int col = wc * 64 + n * 16 + fr;
      float bias = bkvb[col];
#pragma unroll
      for (int m = 0; m < 4; m++)
#pragma unroll
        for (int r = 0; r < 4; r++) {
          int lrow = m * 16 + gg * 4 + r;
          KVt[lrow * 256 + col] = f2bfb(acc[m][n][r] + bias);
        }
    }
    __syncthreads();
    float na = 1.0f / (1.0f + __expf(-nl[0]));
    float nb = 1.0f - na;
#pragma unroll
    for (int it = 0; it < 16; it++) {
      int idx = it * 256 + tid;
      int row = idx >> 6, d = idx & 63;
      int t = t0 + row;
      float k1 = bfb2f(KVt[row * 256 + d]);
      float k2 = bfb2f(KVt[row * 256 + 64 + d]);
      float cv = cosb[t * 64 + d], sv = sinb[t * 64 + d];
      float p1 = k1 * cv - k2 * sv;
      float p2 = k2 * cv + k1 * sv;
      unsigned short* kb = Kf + ((size_t)(b * Tc) + t) * Dc;
      kb[d] = f2bfb(na * k1 + nb * p1);
      kb[64 + d] = f2bfb(na * k2 + nb * p2);
    }
    {
      int d = tid & 127, half = tid >> 7;
      unsigned short* vb = Vt + ((size_t)(b * Dc) + d) * Tc + t0 + half * 32;
#pragma unroll
      for (int j = 0; j < 8; j++) {
        int tl = half * 32 + j * 4;
        us4 o = { KVt[(tl + 0) * 256 + 128 + d], KVt[(tl + 1) * 256 + 128 + d],
                  KVt[(tl + 2) * 256 + 128 + d], KVt[(tl + 3) * 256 + 128 + d] };
        *(us4*)(vb + j * 4) = o;
      }
    }
    return;
  }

  // ---- gemm2q path (dbuf K-loop)
  constexpr int K = 128, NT = 4;
  unsigned short* AsF = smem;            // [2][4096]
  unsigned short* BsF = smem + 8192;     // [2][4096]
  unsigned short* Qt = smem + 16384;     // [128*128]
  int wg = (bid & 7) * 128 + (bid >> 3);
  int m0 = (wg >> 4) * 128, n0 = (wg & 15) * 128;
  int h = n0 >> 7;
  int b = m0 >> 10, t0 = m0 & 1023;
  int wave = tid >> 6;
  int wr = wave >> 1, wc = wave & 1;
  int srow = tid >> 2;
  int skc = (tid & 3) * 8;
  const unsigned short* Ag0 = Aq + (size_t)(m0 + srow) * K + skc;
  const unsigned short* Ag1 = Aq + (size_t)(m0 + 64 + srow) * K + skc;
  const unsigned short* Bg0 = Btq + (size_t)(n0 + srow) * K + skc;
  const unsigned short* Bg1 = Btq + (size_t)(n0 + 64 + srow) * K + skc;
  f32x4 acc[4][4];
  f32x4 zz = {0.f, 0.f, 0.f, 0.f};
#pragma unroll
  for (int m = 0; m < 4; m++)
#pragma unroll
    for (int n = 0; n < 4; n++) acc[m][n] = zz;
  int fr = lane & 15, fk = (lane >> 4) * 8;

  gload16(Ag0, &AsF[tid * 8]);
  gload16(Ag1, &AsF[2048 + tid * 8]);
  gload16(Bg0, &BsF[tid * 8]);
  gload16(Bg1, &BsF[2048 + tid * 8]);
  __syncthreads();

  for (int t = 0; t < NT; t++) {
    int cur = t & 1, nxt = cur ^ 1;
    if (t + 1 < NT) {
      int kt = (t + 1) * 32;
      gload16(Ag0 + kt, &AsF[nxt * 4096 + tid * 8]);
      gload16(Ag1 + kt, &AsF[nxt * 4096 + 2048 + tid * 8]);
      gload16(Bg0 + kt, &BsF[nxt * 4096 + tid * 8]);
      gload16(Bg1 + kt, &BsF[nxt * 4096 + 2048 + tid * 8]);
    }
    bf16x8 af[4], bfv[4];
#pragma unroll
    for (int i = 0; i < 4; i++)
      af[i] = *(const bf16x8*)&AsF[cur * 4096 + (wr * 64 + i * 16 + fr) * 32 + fk];
#pragma unroll
    for (int i = 0; i < 4; i++)
      bfv[i] = *(const bf16x8*)&BsF[cur * 4096 + (wc * 64 + i * 16 + fr) * 32 + fk];
    __builtin_amdgcn_s_setprio(1);
#pragma unroll
    for (int m = 0; m < 4; m++)
#pragma unroll
      for (int n = 0; n < 4; n++)
        acc[m][n] = __builtin_amdgcn_mfma_f32_16x16x32_bf16(af[m], bfv[n], acc[m][n], 0, 0, 0);
    __builtin_amdgcn_s_setprio(0);
    __syncthreads();
  }
  int gg = lane >> 4;
#pragma unroll
  for (int n = 0; n < 4; n++) {
    int col = wc * 64 + n * 16 + fr;
    float bias = bqb[h * 128 + col];
    int ch = col >> 3, wi = col & 7;
#pragma unroll
    for (int m = 0; m < 4; m++)
#pragma unroll
      for (int r = 0; r < 4; r++) {
        int lrow = wr * 64 + m * 16 + gg * 4 + r;
        Qt[lrow * 128 + ((ch ^ (lrow & 7)) << 3) + wi] = f2bfb(acc[m][n][r] + bias);
      }
  }
  __syncthreads();
  const float SCLQ = 0.08838834764831845f * 1.4426950408889634f;
  float na = 1.0f / (1.0f + __expf(-nl[0]));
  float nb = 1.0f - na;
#pragma unroll
  for (int it = 0; it < 4; it++) {
    int task = it * 256 + tid;
    int lrow = task >> 3, cp = task & 7;
    int t = t0 + lrow;
    bf16x8 v1 = *(const bf16x8*)&Qt[lrow * 128 + ((cp ^ (lrow & 7)) << 3)];
    bf16x8 v2 = *(const bf16x8*)&Qt[lrow * 128 + (((cp + 8) ^ (lrow & 7)) << 3)];
    float4 cA = *(const float4*)(cosb + t * 64 + cp * 8);
    float4 cB = *(const float4*)(cosb + t * 64 + cp * 8 + 4);
    float4 sA = *(const float4*)(sinb + t * 64 + cp * 8);
    float4 sB = *(const float4*)(sinb + t * 64 + cp * 8 + 4);
    float cv[8] = {cA.x, cA.y, cA.z, cA.w, cB.x, cB.y, cB.z, cB.w};
    float sv[8] = {sA.x, sA.y, sA.z, sA.w, sB.x, sB.y, sB.z, sB.w};
    float f1[8], f2[8];
#pragma unroll
    for (int j = 0; j < 8; j++) {
      float q1 = bfb2f((unsigned short)v1[j]);
      float q2 = bfb2f((unsigned short)v2[j]);
      float p1 = q1 * cv[j] - q2 * sv[j];
      float p2 = q2 * cv[j] + q1 * sv[j];
      f1[j] = (na * q1 + nb * p1) * SCLQ;
      f2[j] = (na * q2 + nb * p2) * SCLQ;
    }
    unsigned short* ob = Qf + ((size_t)(b * Hc + h) * Tc + t) * Dc + cp * 8;
    us4 o0 = {f2bfb(f1[0]), f2bfb(f1[1]), f2bfb(f1[2]), f2bfb(f1[3])};
    us4 o1 = {f2bfb(f1[4]), f2bfb(f1[5]), f2bfb(f1[6]), f2bfb(f1[7])};
    us4 o2 = {f2bfb(f2[0]), f2bfb(f2[1]), f2bfb(f2[2]), f2bfb(f2[3])};
    us4 o3 = {f2bfb(f2[4]), f2bfb(f2[5]), f2bfb(f2[6]), f2bfb(f2[7])};
    *(us4*)(ob) = o0;
    *(us4*)(ob + 4) = o1;
    *(us4*)(ob + 64) = o2;
    *(us4*)(ob + 68) = o3;
  }
}

// ---------------- split RMSNorm; sums split-K partials ----------------

__global__ __launch_bounds__(256) void k_norm(const float* __restrict__ A1,
                                              const float* __restrict__ A1b,
                                              const float* __restrict__ bqa,
                                              const float* __restrict__ bkva,
                                              const float* __restrict__ qw,
                                              const float* __restrict__ kvw,
                                              unsigned short* __restrict__ Qn,
                                              unsigned short* __restrict__ Kvn) {
  int wave = threadIdx.x >> 6, lane = threadIdx.x & 63;
  int row = blockIdx.x * 4 + wave;
  const float* a = A1 + (size_t)row * 256;
  const float* a2 = A1b + (size_t)row * 256;
  float x0 = a[lane] + a2[lane] + bqa[lane];
  float x1 = a[64 + lane] + a2[64 + lane] + bqa[64 + lane];
  float ss = x0 * x0 + x1 * x1;
#pragma unroll
  for (int off = 1; off < 64; off <<= 1) ss += __shfl_xor(ss, off);
  float sc = rsqrtf(ss * (1.0f / 128.0f) + 1e-6f);
  Qn[(size_t)row * 128 + lane] = f2bfb(x0 * sc * qw[lane]);
  Qn[(size_t)row * 128 + 64 + lane] = f2bfb(x1 * sc * qw[64 + lane]);
  float y = a[128 + lane] + a2[128 + lane] + bkva[lane];
  float s2 = y * y;
#pragma unroll
  for (int off = 1; off < 64; off <<= 1) s2 += __shfl_xor(s2, off);
  float sc2 = rsqrtf(s2 * (1.0f / 64.0f) + 1e-6f);
  Kvn[(size_t)row * 64 + lane] = f2bfb(y * sc2 * kvw[lane]);
}

// ---------------- flash attention (causal, GQA single KV head) ----------------
// Swapped QK^T, 256 blocks x 512 thr, dbuf K LDS, exp2 softmax.
// NEW (R20, m169 pattern): V NOT staged in LDS — read directly from Vt
// (L2-resident, 256KB/batch, XCD-affine). Removes 16 ds_read_b128 + V staging
// per wave-tile (~40% of LDS pressure). LDS 98 -> 66 KB.

__global__ __launch_bounds__(512, 1) void k_attn(const unsigned short* __restrict__ Qf,
                                                 const unsigned short* __restrict__ Kf,
                                                 const unsigned short* __restrict__ Vt,
                                                 const int* __restrict__ amask,
                                                 unsigned short* __restrict__ O) {
  __shared__ __align__(16) unsigned short Ks[2][64 * 128];   // [s][d] swizzled
  __shared__ __align__(16) unsigned short Plds[8][32 * 64];  // per-wave P [q][k] swz
  __shared__ int s_anyzero;

  int bid = blockIdx.x;
  int b = bid & 7;
  int pr = (bid >> 3) & 1;
  int h = bid >> 4;
  int tid = threadIdx.x;
  int wave = tid >> 6, lane = tid & 63;
  int g = lane >> 4, c = lane & 15;

  const unsigned short* Kp = Kf + (size_t)b * Tc * Dc;
  const unsigned short* Vp = Vt + (size_t)b * Dc * Tc;
  const int* mp = amask + b * Tc;
  char* PwB = (char*)&Plds[wave][0];
  f32x4 zz = {0.f, 0.f, 0.f, 0.f};

  if (tid == 0) s_anyzero = 0;
  __syncthreads();
  if (mp[tid] == 0 || mp[tid + 512] == 0) s_anyzero = 1;
  __syncthreads();
  bool anyz = (s_anyzero != 0);

  int kr_ = tid >> 3, kc_ = tid & 7;
  int kidx0 = kr_ * 128 + ((kc_ ^ (kr_ & 7)) << 3);
  int kidx1 = kr_ * 128 + (((kc_ + 8) ^ (kr_ & 7)) << 3);

  int c7s = (c & 7) << 4;
  int g4 = g * 4;

  for (int pass = 0; pass < 2; pass++) {
    int sp = (pass == 0) ? pr : 3 - pr;   // supertile: {0,3} or {1,2}
    int qw0 = sp * 256 + wave * 32;
    int nt = (sp + 1) * 4;
    const unsigned short* Qp = Qf + ((size_t)(b * Hc + h) * Tc + qw0) * Dc;
    bf16x8 qfr[2][4];
#pragma unroll
    for (int m = 0; m < 2; m++)
#pragma unroll
      for (int ks = 0; ks < 4; ks++)
        qfr[m][ks] = *(const bf16x8*)(Qp + (size_t)(m * 16 + c) * Dc + ks * 32 + g * 8);

    f32x4 Oacc[2][8];
#pragma unroll
    for (int m = 0; m < 2; m++)
#pragma unroll
      for (int i = 0; i < 8; i++) Oacc[m][i] = zz;
    float m_r[2] = {-1e30f, -1e30f};
    float l_r[2] = {0.f, 0.f};

    // prologue: stage K tile 0 into buf 0
    bf16x8 krg[2];
    krg[0] = *(const bf16x8*)(Kp + (size_t)kr_ * Dc + kc_ * 8);
    krg[1] = *(const bf16x8*)(Kp + (size_t)kr_ * Dc + kc_ * 8 + 64);
    __syncthreads();  // pass 1: prev-pass Ks reads done
    *(bf16x8*)&Ks[0][kidx0] = krg[0];
    *(bf16x8*)&Ks[0][kidx1] = krg[1];
    __syncthreads();  // buf0 staged

    for (int st = 0; st < nt; st++) {
      int cur = st & 1;
      int s0 = st << 6;
      if (st + 1 < nt) {  // prefetch next K tile
        int s1 = s0 + 64;
        krg[0] = *(const bf16x8*)(Kp + (size_t)(s1 + kr_) * Dc + kc_ * 8);
        krg[1] = *(const bf16x8*)(Kp + (size_t)(s1 + kr_) * Dc + kc_ * 8 + 64);
      }

      if (s0 <= qw0 + 31) {
        const unsigned short* Kc = &Ks[cur][0];

        // ---- swapped QK^T: lane (g,c) holds S[q=qw0+m*16+c][k=s0+j*16+g4+r]
        f32x4 S[2][4];
#pragma unroll
        for (int m = 0; m < 2; m++)
#pragma unroll
          for (int j = 0; j < 4; j++) S[m][j] = zz;
        __builtin_amdgcn_s_setprio(1);
#pragma unroll
        for (int ks = 0; ks < 4; ks++)
#pragma unroll
          for (int j = 0; j < 4; j++) {
            bf16x8 kfr = *(const bf16x8*)&Kc[(j * 16 + c) * 128 + (((ks * 4 + g) ^ (c & 7)) << 3)];
            S[0][j] = __builtin_amdgcn_mfma_f32_16x16x32_bf16(kfr, qfr[0][ks], S[0][j], 0, 0, 0);
            S[1][j] = __builtin_amdgcn_mfma_f32_16x16x32_bf16(kfr, qfr[1][ks], S[1][j], 0, 0, 0);
          }
        __builtin_amdgcn_s_setprio(0);

        if (anyz) {
#pragma unroll
          for (int j = 0; j < 4; j++)
#pragma unroll
            for (int r = 0; r < 4; r++) {
              float madd = (mp[s0 + j * 16 + g4 + r] == 0) ? -2e9f : 0.0f;
              S[0][j][r] += madd;
              S[1][j][r] += madd;
            }
        }
        if (s0 + 63 > qw0) {  // causal edge: mask k > q
#pragma unroll
          for (int j = 0; j < 4; j++) {
            int kk = s0 + j * 16 + g4;
#pragma unroll
            for (int r = 0; r < 4; r++) {
#pragma unroll
              for (int m = 0; m < 2; m++)
                if (kk + r > qw0 + m * 16 + c) S[m][j][r] = -1e30f;
            }
          }
        }

        // ---- tile max per q-row: lane-local 15 fmax + 2 shfl cross-g
        float tmax[2];
#pragma unroll
        for (int m = 0; m < 2; m++) {
          float t0 = fmaxf(fmaxf(S[m][0][0], S[m][0][1]), fmaxf(S[m][0][2], S[m][0][3]));
          float t1 = fmaxf(fmaxf(S[m][1][0], S[m][1][1]), fmaxf(S[m][1][2], S[m][1][3]));
          float t2 = fmaxf(fmaxf(S[m][2][0], S[m][2][1]), fmaxf(S[m][2][2], S[m][2][3]));
          float t3 = fmaxf(fmaxf(S[m][3][0], S[m][3][1]), fmaxf(S[m][3][2], S[m][3][3]));
          float t = fmaxf(fmaxf(t0, t1), fmaxf(t2, t3));
          t = fmaxf(t, __shfl_xor(t, 16));
          t = fmaxf(t, __shfl_xor(t, 32));
          tmax[m] = t;
        }
        bool upd = (tmax[0] > m_r[0] + 11.0f) || (tmax[1] > m_r[1] + 11.0f);
        if (__any(upd)) {
#pragma unroll
          for (int m = 0; m < 2; m++) {
            float mn = fmaxf(m_r[m], tmax[m]);
            float al = fexp2(m_r[m] - mn);
            m_r[m] = mn;
            l_r[m] *= al;
#pragma unroll
            for (int r = 0; r < 4; r++) {
              float alr = __shfl(al, (lane & 48) | (g4 + r));
#pragma unroll
              for (int j2 = 0; j2 < 8; j2++) Oacc[m][j2][r] *= alr;
            }
          }
        }

        // ---- exp + per-lane l partial + P -> LDS (b64 writes, swizzled)
#pragma unroll
        for (int m = 0; m < 2; m++) {
          int rowb = (m * 16 + c) * 128;
#pragma unroll
          for (int j = 0; j < 4; j++) {
            float e0 = fexp2(S[m][j][0] - m_r[m]);
            float e1 = fexp2(S[m][j][1] - m_r[m]);
            float e2 = fexp2(S[m][j][2] - m_r[m]);
            float e3 = fexp2(S[m][j][3] - m_r[m]);
            l_r[m] += (e0 + e1) + (e2 + e3);
            uint2 w;
            w.x = pkbf(e0, e1);
            w.y = pkbf(e2, e3);
            int inrow = (j * 32 + g * 8) ^ c7s;
            *(uint2*)(PwB + rowb + inrow) = w;
          }
        }

        // ---- PV: O += P[32q x 64s] @ V^T ; V read DIRECT from global (L2)
        asm volatile("s_waitcnt lgkmcnt(0)" ::: "memory");
        bf16x8 pa[2][2];
#pragma unroll
        for (int m = 0; m < 2; m++)
#pragma unroll
          for (int sk = 0; sk < 2; sk++)
            pa[m][sk] = *(const bf16x8*)(PwB + (m * 16 + c) * 128 + (((sk * 64 + g * 16)) ^ c7s));
        __builtin_amdgcn_s_setprio(1);
#pragma unroll
        for (int sk = 0; sk < 2; sk++)
#pragma unroll
          for (int j2 = 0; j2 < 8; j2++) {
            bf16x8 vfr = *(const bf16x8*)(Vp + (size_t)(j2 * 16 + c) * Tc + s0 + sk * 32 + g * 8);
            Oacc[0][j2] = __builtin_amdgcn_mfma_f32_16x16x32_bf16(pa[0][sk], vfr, Oacc[0][j2], 0, 0, 0);
            Oacc[1][j2] = __builtin_amdgcn_mfma_f32_16x16x32_bf16(pa[1][sk], vfr, Oacc[1][j2], 0, 0, 0);
          }
        __builtin_amdgcn_s_setprio(0);
      }

      if (st + 1 < nt) {  // write next K tile into the other buffer
        int nxt = cur ^ 1;
        *(bf16x8*)&Ks[nxt][kidx0] = krg[0];
        *(bf16x8*)&Ks[nxt][kidx1] = krg[1];
      }
      __syncthreads();  // one barrier per tile
    }

    // ---- epilogue: cross-g l reduce, broadcast inv, store
#pragma unroll
    for (int m = 0; m < 2; m++) {
      float lt = l_r[m];
      lt += __shfl_xor(lt, 16);
      lt += __shfl_xor(lt, 32);
      float inv = 1.0f / lt;
#pragma unroll
      for (int r = 0; r < 4; r++) {
        float invr = __shfl(inv, (lane & 48) | (g4 + r));
        int qr = qw0 + m * 16 + g4 + r;
        unsigned short* ob = O + ((size_t)(b * Tc) + qr) * HIDc + h * Dc;
#pragma unroll
        for (int j2 = 0; j2 < 8; j2++) ob[j2 * 16 + c] = f2bfb(Oacc[m][j2][r] * invr);
      }
    }
  }
}

// ---------------- host launch ----------------

extern "C" void kernel_launch(void* const* d_in, const int* in_sizes, int n_in,
                              void* d_out, int out_size, void* d_ws, size_t ws_size,
                              hipStream_t stream) {
  const float* h = (const float*)d_in[0];
  const float* cg = (const float*)d_in[1];
  const float* sg = (const float*)d_in[2];
  const float* cl = (const float*)d_in[3];
  const float* sl = (const float*)d_in[4];
  const float* Wq_a = (const float*)d_in[5];
  const float* bq_a = (const float*)d_in[6];
  const float* Wq_b = (const float*)d_in[7];
  const float* bq_b = (const float*)d_in[8];
  const float* Wkv_a = (const float*)d_in[9];
  const float* bkv_a = (const float*)d_in[10];
  const float* Wkv_b = (const float*)d_in[11];
  const float* bkv_b = (const float*)d_in[12];
  const float* qw = (const float*)d_in[13];
  const float* kvw = (const float*)d_in[14];
  const float* Wo = (const float*)d_in[15];
  const float* nl = (const float*)d_in[16];
  const float* gl = (const float*)d_in[17];
  const int* am = (const int*)d_in[18];
  float* out = (float*)d_out;
  char* ws = (char*)d_ws;

  // ws layout (bytes); Obuf at 0; A1b in freed region
  const size_t o_hB = 0;             // bf16 [8192][2048]  33554432  (Obuf)
  const size_t o_A1b = 33554432;     // f32  [8192][256]    8388608  (split-K partial)
  const size_t o_Qf = 67108864;      // bf16 [B][H][T][D]  33554432
  const size_t o_A1 = 100663296;     // f32  [8192][256]    8388608
  const size_t o_Qn = 109051904;     // bf16 [8192][128]    2097152
  const size_t o_Kvn = 111149056;    // bf16 [8192][64]     1048576
  const size_t o_Kf = 116391936;     // bf16 [8192][128]    2097152
  const size_t o_Vt = 118489088;     // bf16 [B*128][1024]  2097152
  const size_t o_W1t = 120586240;    // bf16 [256][2048]    1048576
  const size_t o_Wqbt = 121634816;   // bf16 [2048][128]     524288
  const size_t o_Wkbt = 122159104;   // bf16 [256][64]        32768
  const size_t o_Wot = 122191872;    // bf16 [2048][2048]   8388608
  const size_t o_cos = 130580480;    // f32  [65536]         262144
  const size_t o_sin = 130842624;    // f32  [65536]         262144

  unsigned short* Obuf = (unsigned short*)(ws + o_hB);
  float* A1b = (float*)(ws + o_A1b);
  unsigned short* Qf = (unsigned short*)(ws + o_Qf);
  float* A1 = (float*)(ws + o_A1);
  unsigned short* Qn = (unsigned short*)(ws + o_Qn);
  unsigned short* Kvn = (unsigned short*)(ws + o_Kvn);
  unsigned short* Kf = (unsigned short*)(ws + o_Kf);
  unsigned short* Vt = (unsigned short*)(ws + o_Vt);
  unsigned short* W1t = (unsigned short*)(ws + o_W1t);
  unsigned short* Wqbt = (unsigned short*)(ws + o_Wqbt);
  unsigned short* Wkbt = (unsigned short*)(ws + o_Wkbt);
  unsigned short* Wot = (unsigned short*)(ws + o_Wot);
  float* cosb = (float*)(ws + o_cos);
  float* sinb = (float*)(ws + o_sin);

  (void)in_sizes; (void)n_in; (void)out_size; (void)ws_size;

  // prep1: small transposes + blend + zero (W1t needed by gemm1)
  k_prep1<<<1424, 256, 0, stream>>>(Wq_a, Wkv_a, Wq_b, Wkv_b,
                                    cg, sg, cl, sl, gl,
                                    W1t, Wqbt, Wkbt, cosb, sinb);
  // gemm1 (512 blocks) + Wo transpose backfill (4096 blocks)
  k_g1wo<<<4608, 256, 0, stream>>>(h, W1t, A1, A1b, Wo, Wot);
  // split rmsnorm (sums partials)
  k_norm<<<2048, 256, 0, stream>>>(A1, A1b, bq_a, bkv_a, qw, kvw, Qn, Kvn);
  // gemm2q (1024 blocks) + gemm2kv (128 blocks) in one launch
  k_g2<<<1152, 256, 0, stream>>>(Qn, Wqbt, bq_b, Kvn, Wkbt, bkv_b,
                                 cosb, sinb, nl, Qf, Kf, Vt);
  // attention: 256 blocks (h*16 + pair*8 + b) x 512 threads (V direct-from-L2)
  k_attn<<<256, 512, 0, stream>>>(Qf, Kf, Vt, am, Obuf);
  // GEMM3: 256^2 BK=64 2-slice counted-vmcnt pipeline -> fp32 out
  k_gemm3<<<256, 512, 0, stream>>>(Obuf, Wot, out);
}

// Round 21
// 187.039 us; speedup vs baseline: 1.2250x; 1.2250x over previous
//
#include <hip/hip_runtime.h>
#include <hip/hip_bf16.h>

typedef __attribute__((ext_vector_type(8))) short bf16x8;
typedef __attribute__((ext_vector_type(4))) float f32x4;
typedef __attribute__((ext_vector_type(4))) unsigned short us4;

#define DEV __device__ __forceinline__

constexpr int Bc = 8, Tc = 1024, HIDc = 2048, Hc = 16, Dc = 128;
constexpr int ROWSc = Bc * Tc;  // 8192

DEV unsigned short f2bfb(float x) {
  union { float f; unsigned u; } v; v.f = x;
  unsigned r = v.u + 0x7fffu + ((v.u >> 16) & 1u);  // round-to-nearest-even
  return (unsigned short)(r >> 16);
}
DEV float bfb2f(unsigned short b) {
  union { unsigned u; float f; } v; v.u = ((unsigned)b) << 16; return v.f;
}
DEV float fexp2(float x) { return __builtin_amdgcn_exp2f(x); }  // native v_exp_f32
DEV unsigned pkbf(float lo, float hi) {  // 2 bf16 (round-half-up) packed in u32
  union { float f; unsigned u; } a, b; a.f = lo; b.f = hi;
  return ((b.u + 0x8000u) & 0xffff0000u) | ((a.u + 0x8000u) >> 16);
}

// async global->LDS, 16B per lane; LDS dest MUST be linear in lane order
// (wave-uniform base + lane*16) — rule 21 / m104.
DEV void gload16(const void* g, void* l) {
  __builtin_amdgcn_global_load_lds(
      (const __attribute__((address_space(1))) unsigned int*)g,
      (__attribute__((address_space(3))) unsigned int*)l, 16, 0, 0);
}

// 32x32 fp32->bf16 transpose tile helper (tile = 32x33 floats in LDS)
DEV void tr32(const float* __restrict__ in, unsigned short* __restrict__ out,
              int R, int C, int bx, int by, float (*tile)[33], int tx, int ty) {
  int r0 = by * 32, c0 = bx * 32;
#pragma unroll
  for (int i = 0; i < 4; i++)
    tile[ty + i * 8][tx] = in[(size_t)(r0 + ty + i * 8) * C + c0 + tx];
  __syncthreads();
#pragma unroll
  for (int i = 0; i < 4; i++) {
    int rr = ty + i * 8;
    out[(size_t)(c0 + rr) * R + r0 + tx] = f2bfb(tile[tx][rr]);
  }
}

// ---------------- prep1: small transposes + blend + zero (1424 blocks) ----------------

__global__ __launch_bounds__(256) void k_prep1(
    const float* __restrict__ Wq_a, const float* __restrict__ Wkv_a,
    const float* __restrict__ Wq_b, const float* __restrict__ Wkv_b,
    const float* __restrict__ cg, const float* __restrict__ sg,
    const float* __restrict__ cl, const float* __restrict__ sl,
    const float* __restrict__ gl,
    unsigned short* __restrict__ W1t, unsigned short* __restrict__ Wqbt,
    unsigned short* __restrict__ Wkbt,
    float* __restrict__ cosb, float* __restrict__ sinb) {
  __shared__ float tile[32][33];
  int bid = blockIdx.x;
  int tid = threadIdx.x;
  int tx = tid & 31, ty = tid >> 5;
  if (bid < 256) {
    tr32(Wq_a, W1t, 2048, 128, bid & 3, bid >> 2, tile, tx, ty);
  } else if (bid < 384) {
    int i = bid - 256;
    tr32(Wkv_a, W1t + (size_t)128 * 2048, 2048, 64, i & 1, i >> 1, tile, tx, ty);
  } else if (bid < 640) {
    int i = bid - 384;
    tr32(Wq_b, Wqbt, 128, 2048, i & 63, i >> 6, tile, tx, ty);
  } else if (bid < 656) {
    int i = bid - 640;
    tr32(Wkv_b, Wkbt, 64, 256, i & 7, i >> 3, tile, tx, ty);
  } else if (bid < 912) {
    int u = (bid - 656) * 256 + tid;  // < 65536
    float a = 1.0f / (1.0f + __expf(-gl[0]));
    cosb[u] = cg[u] * a + cl[u] * (1.0f - a);
    sinb[u] = sg[u] * a + sl[u] * (1.0f - a);
  } else {
    int i = (bid - 912) * 256 + tid;  // < 131072
    W1t[(size_t)192 * 2048 + i] = 0;
  }
}

// ---------------- g1wo: GEMM1 (split-K2 dbuf) + Wo transpose backfill ----------------

__global__ __launch_bounds__(256) void k_g1wo(const float* __restrict__ A,
                                              const unsigned short* __restrict__ Bt,
                                              float* __restrict__ C0,
                                              float* __restrict__ C1,
                                              const float* __restrict__ Wo,
                                              unsigned short* __restrict__ Wot) {
  constexpr int K = 2048, N = 256, KH = 1024, NT = KH / 32;
  __shared__ __align__(16) unsigned short smem[12288];  // 24 KB union
  int bid = blockIdx.x;
  int tid = threadIdx.x;

  if (bid >= 512) {  // ---- Wo transpose path
    int i = bid - 512;
    float (*tile)[33] = (float(*)[33])smem;
    tr32(Wo, Wot, 2048, 2048, i & 63, i >> 6, tile, tid & 31, tid >> 5);
    return;
  }

  // ---- gemm1 path
  unsigned short* AlsF = smem;          // [2][2048]
  unsigned short* BlsF = smem + 4096;   // [2][4096]
  int wg = (bid & 7) * 64 + (bid >> 3);
  int ksl = wg & 1;
  int nti = (wg >> 1) & 1;
  int mti = wg >> 2;
  int m0 = mti * 64, n0 = nti * 128, k0 = ksl * KH;
  float* C = ksl ? C1 : C0;
  int lane = tid & 63, wc = tid >> 6;
  int ar = tid >> 2, akc = (tid & 3) * 8;
  const float* Ag = A + (size_t)(m0 + ar) * K + k0 + akc;
  const unsigned short* Bg0 = Bt + (size_t)(n0 + ar) * K + k0 + akc;
  const unsigned short* Bg1 = Bt + (size_t)(n0 + 64 + ar) * K + k0 + akc;
  f32x4 acc[4][2];
  f32x4 zz = {0.f, 0.f, 0.f, 0.f};
#pragma unroll
  for (int m = 0; m < 4; m++)
#pragma unroll
    for (int n = 0; n < 2; n++) acc[m][n] = zz;
  int fr = lane & 15, fk = (lane >> 4) * 8;

  float4 a0 = *(const float4*)(Ag);
  float4 a1 = *(const float4*)(Ag + 4);
  gload16(Bg0, &BlsF[tid * 8]);
  gload16(Bg1, &BlsF[2048 + tid * 8]);
  {
    us4 c0v = { f2bfb(a0.x), f2bfb(a0.y), f2bfb(a0.z), f2bfb(a0.w) };
    us4 c1v = { f2bfb(a1.x), f2bfb(a1.y), f2bfb(a1.z), f2bfb(a1.w) };
    *(us4*)&AlsF[ar * 32 + akc] = c0v;
    *(us4*)&AlsF[ar * 32 + akc + 4] = c1v;
  }
  a0 = *(const float4*)(Ag + 32);
  a1 = *(const float4*)(Ag + 36);
  __syncthreads();  // buf0 staged

  for (int t = 0; t < NT; t++) {
    int cur = t & 1, nxt = cur ^ 1;
    if (t + 1 < NT) {
      gload16(Bg0 + (t + 1) * 32, &BlsF[nxt * 4096 + tid * 8]);
      gload16(Bg1 + (t + 1) * 32, &BlsF[nxt * 4096 + 2048 + tid * 8]);
    }
    bf16x8 af[4], bfv[2];
#pragma unroll
    for (int i = 0; i < 4; i++)
      af[i] = *(const bf16x8*)&AlsF[cur * 2048 + (i * 16 + fr) * 32 + fk];
#pragma unroll
    for (int i = 0; i < 2; i++)
      bfv[i] = *(const bf16x8*)&BlsF[cur * 4096 + (wc * 32 + i * 16 + fr) * 32 + fk];
    __builtin_amdgcn_s_setprio(1);
#pragma unroll
    for (int m = 0; m < 4; m++)
#pragma unroll
      for (int n = 0; n < 2; n++)
        acc[m][n] = __builtin_amdgcn_mfma_f32_16x16x32_bf16(af[m], bfv[n], acc[m][n], 0, 0, 0);
    __builtin_amdgcn_s_setprio(0);
    if (t + 1 < NT) {
      us4 d0 = { f2bfb(a0.x), f2bfb(a0.y), f2bfb(a0.z), f2bfb(a0.w) };
      us4 d1 = { f2bfb(a1.x), f2bfb(a1.y), f2bfb(a1.z), f2bfb(a1.w) };
      *(us4*)&AlsF[nxt * 2048 + ar * 32 + akc] = d0;
      *(us4*)&AlsF[nxt * 2048 + ar * 32 + akc + 4] = d1;
    }
    if (t + 2 < NT) {
      a0 = *(const float4*)(Ag + (t + 2) * 32);
      a1 = *(const float4*)(Ag + (t + 2) * 32 + 4);
    }
    __syncthreads();
  }
  int gg = lane >> 4;
#pragma unroll
  for (int m = 0; m < 4; m++)
#pragma unroll
    for (int n = 0; n < 2; n++)
#pragma unroll
      for (int r = 0; r < 4; r++) {
        size_t row = (size_t)m0 + m * 16 + gg * 4 + r;
        size_t col = (size_t)n0 + wc * 32 + n * 16 + fr;
        C[row * N + col] = acc[m][n][r];
      }
}

// ---------------- GEMM3: 256x256 tile, BK=64 (2 K-slices), counted-vmcnt ----------------

__global__ __launch_bounds__(512, 2) void k_gemm3(const unsigned short* __restrict__ A,
                                                  const unsigned short* __restrict__ Bt,
                                                  float* __restrict__ C) {
  constexpr int K = 2048, N = 2048, NT = K / 64;
  __shared__ __align__(16) unsigned short Als[2][2][8192];
  __shared__ __align__(16) unsigned short Bls[2][2][8192];
  int lin = blockIdx.x;
  int wg = (lin & 7) * 32 + (lin >> 3);   // XCD-contiguous
  int m0 = (wg >> 3) * 256, n0 = (wg & 7) * 256;
  int tid = threadIdx.x, lane = tid & 63, wave = tid >> 6;
  int wm = wave >> 2, wn = wave & 3;
  int g = lane >> 4, c = lane & 15;

  int rb = tid >> 2;
  int sch = (tid & 3) ^ ((tid >> 3) & 3);
  const unsigned short* Ag = A + (size_t)(m0 + rb) * K + sch * 8;
  const unsigned short* Bg = Bt + (size_t)(n0 + rb) * K + sch * 8;
  const int gsw = (g ^ ((c >> 1) & 3)) * 8;

  f32x4 acc[8][4];
  f32x4 zz = {0.f, 0.f, 0.f, 0.f};
#pragma unroll
  for (int mi = 0; mi < 8; mi++)
#pragma unroll
    for (int ni = 0; ni < 4; ni++) acc[mi][ni] = zz;

#pragma unroll
  for (int sl = 0; sl < 2; sl++) {
    gload16(Ag + sl * 32, &Als[0][sl][tid * 8]);
    gload16(Ag + (size_t)128 * K + sl * 32, &Als[0][sl][4096 + tid * 8]);
    gload16(Bg + sl * 32, &Bls[0][sl][tid * 8]);
    gload16(Bg + (size_t)128 * K + sl * 32, &Bls[0][sl][4096 + tid * 8]);
  }

  for (int t = 0; t < NT; ++t) {
    int buf = t & 1, nb = buf ^ 1;
    bool nl = (t + 1 < NT);
    int nkt = (t + 1) * 64;
#pragma unroll
    for (int sl = 0; sl < 2; sl++) {
      if (sl == 0 || nl) {
        asm volatile("s_waitcnt vmcnt(4)" ::: "memory");
      } else {
        asm volatile("s_waitcnt vmcnt(0)" ::: "memory");
      }
      __builtin_amdgcn_sched_barrier(0);
      __builtin_amdgcn_s_barrier();
      __builtin_amdgcn_sched_barrier(0);
      const unsigned short* As_ = &Als[buf][sl][0];
      const unsigned short* Bs_ = &Bls[buf][sl][0];
      bf16x8 af[8], bfv[4];
#pragma unroll
      for (int mi = 0; mi < 8; mi++)
        af[mi] = *(const bf16x8*)&As_[(wm * 128 + mi * 16 + c) * 32 + gsw];
#pragma unroll
      for (int ni = 0; ni < 4; ni++)
        bfv[ni] = *(const bf16x8*)&Bs_[(wn * 64 + ni * 16 + c) * 32 + gsw];
      if (nl) {
        gload16(Ag + nkt + sl * 32, &Als[nb][sl][tid * 8]);
        gload16(Ag + (size_t)128 * K + nkt + sl * 32, &Als[nb][sl][4096 + tid * 8]);
      }
      __builtin_amdgcn_s_setprio(1);
#pragma unroll
      for (int mi = 0; mi < 8; mi++) {
        acc[mi][0] = __builtin_amdgcn_mfma_f32_16x16x32_bf16(af[mi], bfv[0], acc[mi][0], 0, 0, 0);
        acc[mi][1] = __builtin_amdgcn_mfma_f32_16x16x32_bf16(af[mi], bfv[1], acc[mi][1], 0, 0, 0);
      }
      __builtin_amdgcn_s_setprio(0);
      if (nl) {
        gload16(Bg + nkt + sl * 32, &Bls[nb][sl][tid * 8]);
        gload16(Bg + (size_t)128 * K + nkt + sl * 32, &Bls[nb][sl][4096 + tid * 8]);
      }
      __builtin_amdgcn_s_setprio(1);
#pragma unroll
      for (int mi = 0; mi < 8; mi++) {
        acc[mi][2] = __builtin_amdgcn_mfma_f32_16x16x32_bf16(af[mi], bfv[2], acc[mi][2], 0, 0, 0);
        acc[mi][3] = __builtin_amdgcn_mfma_f32_16x16x32_bf16(af[mi], bfv[3], acc[mi][3], 0, 0, 0);
      }
      __builtin_amdgcn_s_setprio(0);
    }
  }

#pragma unroll
  for (int mi = 0; mi < 8; mi++)
#pragma unroll
    for (int ni = 0; ni < 4; ni++)
#pragma unroll
      for (int r = 0; r < 4; r++) {
        size_t row = (size_t)m0 + wm * 128 + mi * 16 + g * 4 + r;
        size_t col = (size_t)n0 + wn * 64 + ni * 16 + c;
        C[row * N + col] = acc[mi][ni][r];
      }
}

// ---------------- g2: GEMM2a+RoPE-Q (blocks 0..1023) + GEMM2b+RoPE-K/V (1024..1151) ----------------

__global__ __launch_bounds__(256) void k_g2(const unsigned short* __restrict__ Aq,
                                            const unsigned short* __restrict__ Btq,
                                            const float* __restrict__ bqb,
                                            const unsigned short* __restrict__ Akv,
                                            const unsigned short* __restrict__ Btkv,
                                            const float* __restrict__ bkvb,
                                            const float* __restrict__ cosb,
                                            const float* __restrict__ sinb,
                                            const float* __restrict__ nl,
                                            unsigned short* __restrict__ Qf,
                                            unsigned short* __restrict__ Kf,
                                            unsigned short* __restrict__ Vt) {
  __shared__ __align__(16) unsigned short smem[36864];  // 72 KB union
  int bid = blockIdx.x;
  int tid = threadIdx.x;
  int lane = tid & 63;

  if (bid >= 1024) {  // ---- gemm2kv path
    unsigned short* As2 = smem;           // [64*64]
    unsigned short* Bs2 = smem + 4096;    // [256*64]
    unsigned short* KVt = smem + 20480;   // [64*256]
    int m0 = (bid - 1024) * 64;
    int b = m0 >> 10, t0 = m0 & 1023;
    int wc = tid >> 6;
    int fr = lane & 15, gg = lane >> 4;
#pragma unroll
    for (int p = 0; p < 2; p++) {
      int slot = p * 256 + tid;
      int row = slot >> 3, chpos = slot & 7;
      gload16(Akv + (size_t)(m0 + row) * 64 + ((chpos ^ (row & 7)) << 3),
              &As2[slot * 8]);
    }
#pragma unroll
    for (int p = 0; p < 8; p++) {
      int slot = p * 256 + tid;
      int row = slot >> 3, chpos = slot & 7;
      gload16(Btkv + (size_t)row * 64 + ((chpos ^ (row & 7)) << 3),
              &Bs2[slot * 8]);
    }
    __syncthreads();
    f32x4 acc[4][4];
    f32x4 zz = {0.f, 0.f, 0.f, 0.f};
#pragma unroll
    for (int m = 0; m < 4; m++)
#pragma unroll
      for (int n = 0; n < 4; n++) acc[m][n] = zz;
#pragma unroll
    for (int ks = 0; ks < 2; ks++) {
      bf16x8 af[4], bfv[4];
#pragma unroll
      for (int m = 0; m < 4; m++) {
        int row = m * 16 + fr;
        af[m] = *(const bf16x8*)&As2[row * 64 + (((ks * 4 + gg) ^ (row & 7)) << 3)];
      }
#pragma unroll
      for (int n = 0; n < 4; n++) {
        int row = wc * 64 + n * 16 + fr;
        bfv[n] = *(const bf16x8*)&Bs2[row * 64 + (((ks * 4 + gg) ^ (row & 7)) << 3)];
      }
#pragma unroll
      for (int m = 0; m < 4; m++)
#pragma unroll
        for (int n = 0; n < 4; n++)
          acc[m][n] = __builtin_amdgcn_mfma_f32_16x16x32_bf16(af[m], bfv[n], acc[m][n], 0, 0, 0);
    }
#pragma unroll
    for (int n = 0; n < 4; n++) {
      int col = wc * 64 + n * 16 + fr;
      float bias = bkvb[col];
#pragma unroll
      for (int m = 0; m < 4; m++)
#pragma unroll
        for (int r = 0; r < 4; r++) {
          int lrow = m * 16 + gg * 4 + r;
          KVt[lrow * 256 + col] = f2bfb(acc[m][n][r] + bias);
        }
    }
    __syncthreads();
    float na = 1.0f / (1.0f + __expf(-nl[0]));
    float nb = 1.0f - na;
#pragma unroll
    for (int it = 0; it < 16; it++) {
      int idx = it * 256 + tid;
      int row = idx >> 6, d = idx & 63;
      int t = t0 + row;
      float k1 = bfb2f(KVt[row * 256 + d]);
      float k2 = bfb2f(KVt[row * 256 + 64 + d]);
      float cv = cosb[t * 64 + d], sv = sinb[t * 64 + d];
      float p1 = k1 * cv - k2 * sv;
      float p2 = k2 * cv + k1 * sv;
      unsigned short* kb = Kf + ((size_t)(b * Tc) + t) * Dc;
      kb[d] = f2bfb(na * k1 + nb * p1);
      kb[64 + d] = f2bfb(na * k2 + nb * p2);
    }
    {
      int d = tid & 127, half = tid >> 7;
      unsigned short* vb = Vt + ((size_t)(b * Dc) + d) * Tc + t0 + half * 32;
#pragma unroll
      for (int j = 0; j < 8; j++) {
        int tl = half * 32 + j * 4;
        us4 o = { KVt[(tl + 0) * 256 + 128 + d], KVt[(tl + 1) * 256 + 128 + d],
                  KVt[(tl + 2) * 256 + 128 + d], KVt[(tl + 3) * 256 + 128 + d] };
        *(us4*)(vb + j * 4) = o;
      }
    }
    return;
  }

  // ---- gemm2q path (dbuf K-loop)
  constexpr int K = 128, NT = 4;
  unsigned short* AsF = smem;            // [2][4096]
  unsigned short* BsF = smem + 8192;     // [2][4096]
  unsigned short* Qt = smem + 16384;     // [128*128]
  int wg = (bid & 7) * 128 + (bid >> 3);
  int m0 = (wg >> 4) * 128, n0 = (wg & 15) * 128;
  int h = n0 >> 7;
  int b = m0 >> 10, t0 = m0 & 1023;
  int wave = tid >> 6;
  int wr = wave >> 1, wc = wave & 1;
  int srow = tid >> 2;
  int skc = (tid & 3) * 8;
  const unsigned short* Ag0 = Aq + (size_t)(m0 + srow) * K + skc;
  const unsigned short* Ag1 = Aq + (size_t)(m0 + 64 + srow) * K + skc;
  const unsigned short* Bg0 = Btq + (size_t)(n0 + srow) * K + skc;
  const unsigned short* Bg1 = Btq + (size_t)(n0 + 64 + srow) * K + skc;
  f32x4 acc[4][4];
  f32x4 zz = {0.f, 0.f, 0.f, 0.f};
#pragma unroll
  for (int m = 0; m < 4; m++)
#pragma unroll
    for (int n = 0; n < 4; n++) acc[m][n] = zz;
  int fr = lane & 15, fk = (lane >> 4) * 8;

  gload16(Ag0, &AsF[tid * 8]);
  gload16(Ag1, &AsF[2048 + tid * 8]);
  gload16(Bg0, &BsF[tid * 8]);
  gload16(Bg1, &BsF[2048 + tid * 8]);
  __syncthreads();

  for (int t = 0; t < NT; t++) {
    int cur = t & 1, nxt = cur ^ 1;
    if (t + 1 < NT) {
      int kt = (t + 1) * 32;
      gload16(Ag0 + kt, &AsF[nxt * 4096 + tid * 8]);
      gload16(Ag1 + kt, &AsF[nxt * 4096 + 2048 + tid * 8]);
      gload16(Bg0 + kt, &BsF[nxt * 4096 + tid * 8]);
      gload16(Bg1 + kt, &BsF[nxt * 4096 + 2048 + tid * 8]);
    }
    bf16x8 af[4], bfv[4];
#pragma unroll
    for (int i = 0; i < 4; i++)
      af[i] = *(const bf16x8*)&AsF[cur * 4096 + (wr * 64 + i * 16 + fr) * 32 + fk];
#pragma unroll
    for (int i = 0; i < 4; i++)
      bfv[i] = *(const bf16x8*)&BsF[cur * 4096 + (wc * 64 + i * 16 + fr) * 32 + fk];
    __builtin_amdgcn_s_setprio(1);
#pragma unroll
    for (int m = 0; m < 4; m++)
#pragma unroll
      for (int n = 0; n < 4; n++)
        acc[m][n] = __builtin_amdgcn_mfma_f32_16x16x32_bf16(af[m], bfv[n], acc[m][n], 0, 0, 0);
    __builtin_amdgcn_s_setprio(0);
    __syncthreads();
  }
  int gg = lane >> 4;
#pragma unroll
  for (int n = 0; n < 4; n++) {
    int col = wc * 64 + n * 16 + fr;
    float bias = bqb[h * 128 + col];
    int ch = col >> 3, wi = col & 7;
#pragma unroll
    for (int m = 0; m < 4; m++)
#pragma unroll
      for (int r = 0; r < 4; r++) {
        int lrow = wr * 64 + m * 16 + gg * 4 + r;
        Qt[lrow * 128 + ((ch ^ (lrow & 7)) << 3) + wi] = f2bfb(acc[m][n][r] + bias);
      }
  }
  __syncthreads();
  const float SCLQ = 0.08838834764831845f * 1.4426950408889634f;
  float na = 1.0f / (1.0f + __expf(-nl[0]));
  float nb = 1.0f - na;
#pragma unroll
  for (int it = 0; it < 4; it++) {
    int task = it * 256 + tid;
    int lrow = task >> 3, cp = task & 7;
    int t = t0 + lrow;
    bf16x8 v1 = *(const bf16x8*)&Qt[lrow * 128 + ((cp ^ (lrow & 7)) << 3)];
    bf16x8 v2 = *(const bf16x8*)&Qt[lrow * 128 + (((cp + 8) ^ (lrow & 7)) << 3)];
    float4 cA = *(const float4*)(cosb + t * 64 + cp * 8);
    float4 cB = *(const float4*)(cosb + t * 64 + cp * 8 + 4);
    float4 sA = *(const float4*)(sinb + t * 64 + cp * 8);
    float4 sB = *(const float4*)(sinb + t * 64 + cp * 8 + 4);
    float cv[8] = {cA.x, cA.y, cA.z, cA.w, cB.x, cB.y, cB.z, cB.w};
    float sv[8] = {sA.x, sA.y, sA.z, sA.w, sB.x, sB.y, sB.z, sB.w};
    float f1[8], f2[8];
#pragma unroll
    for (int j = 0; j < 8; j++) {
      float q1 = bfb2f((unsigned short)v1[j]);
      float q2 = bfb2f((unsigned short)v2[j]);
      float p1 = q1 * cv[j] - q2 * sv[j];
      float p2 = q2 * cv[j] + q1 * sv[j];
      f1[j] = (na * q1 + nb * p1) * SCLQ;
      f2[j] = (na * q2 + nb * p2) * SCLQ;
    }
    unsigned short* ob = Qf + ((size_t)(b * Hc + h) * Tc + t) * Dc + cp * 8;
    us4 o0 = {f2bfb(f1[0]), f2bfb(f1[1]), f2bfb(f1[2]), f2bfb(f1[3])};
    us4 o1 = {f2bfb(f1[4]), f2bfb(f1[5]), f2bfb(f1[6]), f2bfb(f1[7])};
    us4 o2 = {f2bfb(f2[0]), f2bfb(f2[1]), f2bfb(f2[2]), f2bfb(f2[3])};
    us4 o3 = {f2bfb(f2[4]), f2bfb(f2[5]), f2bfb(f2[6]), f2bfb(f2[7])};
    *(us4*)(ob) = o0;
    *(us4*)(ob + 4) = o1;
    *(us4*)(ob + 64) = o2;
    *(us4*)(ob + 68) = o3;
  }
}

// ---------------- split RMSNorm; sums split-K partials ----------------

__global__ __launch_bounds__(256) void k_norm(const float* __restrict__ A1,
                                              const float* __restrict__ A1b,
                                              const float* __restrict__ bqa,
                                              const float* __restrict__ bkva,
                                              const float* __restrict__ qw,
                                              const float* __restrict__ kvw,
                                              unsigned short* __restrict__ Qn,
                                              unsigned short* __restrict__ Kvn) {
  int wave = threadIdx.x >> 6, lane = threadIdx.x & 63;
  int row = blockIdx.x * 4 + wave;
  const float* a = A1 + (size_t)row * 256;
  const float* a2 = A1b + (size_t)row * 256;
  float x0 = a[lane] + a2[lane] + bqa[lane];
  float x1 = a[64 + lane] + a2[64 + lane] + bqa[64 + lane];
  float ss = x0 * x0 + x1 * x1;
#pragma unroll
  for (int off = 1; off < 64; off <<= 1) ss += __shfl_xor(ss, off);
  float sc = rsqrtf(ss * (1.0f / 128.0f) + 1e-6f);
  Qn[(size_t)row * 128 + lane] = f2bfb(x0 * sc * qw[lane]);
  Qn[(size_t)row * 128 + 64 + lane] = f2bfb(x1 * sc * qw[64 + lane]);
  float y = a[128 + lane] + a2[128 + lane] + bkva[lane];
  float s2 = y * y;
#pragma unroll
  for (int off = 1; off < 64; off <<= 1) s2 += __shfl_xor(s2, off);
  float sc2 = rsqrtf(s2 * (1.0f / 64.0f) + 1e-6f);
  Kvn[(size_t)row * 64 + lane] = f2bfb(y * sc2 * kvw[lane]);
}

// ---------------- flash attention (causal, GQA single KV head) ----------------
// R19-proven: swapped QK^T, 256 blocks x 512 thr, dbuf K+V LDS, exp2 softmax.
// (R20 V-direct-from-L2 regressed 67->110us: LDS staging here is latency
// amortization + layout transform, not just BW — keep both staged.)

__global__ __launch_bounds__(512, 1) void k_attn(const unsigned short* __restrict__ Qf,
                                                 const unsigned short* __restrict__ Kf,
                                                 const unsigned short* __restrict__ Vt,
                                                 const int* __restrict__ amask,
                                                 unsigned short* __restrict__ O) {
  __shared__ __align__(16) unsigned short Ks[2][64 * 128];   // [s][d] swizzled
  __shared__ __align__(16) unsigned short Vs[2][128 * 64];   // [d][s] swizzled
  __shared__ __align__(16) unsigned short Plds[8][32 * 64];  // per-wave P [q][k] swz
  __shared__ int s_anyzero;

  int bid = blockIdx.x;
  int b = bid & 7;
  int pr = (bid >> 3) & 1;
  int h = bid >> 4;
  int tid = threadIdx.x;
  int wave = tid >> 6, lane = tid & 63;
  int g = lane >> 4, c = lane & 15;

  const unsigned short* Kp = Kf + (size_t)b * Tc * Dc;
  const unsigned short* Vp = Vt + (size_t)b * Dc * Tc;
  const int* mp = amask + b * Tc;
  char* PwB = (char*)&Plds[wave][0];
  f32x4 zz = {0.f, 0.f, 0.f, 0.f};

  if (tid == 0) s_anyzero = 0;
  __syncthreads();
  if (mp[tid] == 0 || mp[tid + 512] == 0) s_anyzero = 1;
  __syncthreads();
  bool anyz = (s_anyzero != 0);

  int kr_ = tid >> 3, kc_ = tid & 7;
  int vr_ = tid >> 2, vc_ = tid & 3;
  int kidx0 = kr_ * 128 + ((kc_ ^ (kr_ & 7)) << 3);
  int kidx1 = kr_ * 128 + (((kc_ + 8) ^ (kr_ & 7)) << 3);
  int vidx0 = vr_ * 64 + ((vc_ ^ (vr_ & 7)) << 3);
  int vidx1 = vr_ * 64 + (((vc_ + 4) ^ (vr_ & 7)) << 3);

  int c7s = (c & 7) << 4;
  int g4 = g * 4;

  for (int pass = 0; pass < 2; pass++) {
    int sp = (pass == 0) ? pr : 3 - pr;   // supertile: {0,3} or {1,2}
    int qw0 = sp * 256 + wave * 32;
    int nt = (sp + 1) * 4;
    const unsigned short* Qp = Qf + ((size_t)(b * Hc + h) * Tc + qw0) * Dc;
    bf16x8 qfr[2][4];
#pragma unroll
    for (int m = 0; m < 2; m++)
#pragma unroll
      for (int ks = 0; ks < 4; ks++)
        qfr[m][ks] = *(const bf16x8*)(Qp + (size_t)(m * 16 + c) * Dc + ks * 32 + g * 8);

    f32x4 Oacc[2][8];
#pragma unroll
    for (int m = 0; m < 2; m++)
#pragma unroll
      for (int i = 0; i < 8; i++) Oacc[m][i] = zz;
    float m_r[2] = {-1e30f, -1e30f};
    float l_r[2] = {0.f, 0.f};

    bf16x8 krg[2], vrg[2];
    krg[0] = *(const bf16x8*)(Kp + (size_t)kr_ * Dc + kc_ * 8);
    krg[1] = *(const bf16x8*)(Kp + (size_t)kr_ * Dc + kc_ * 8 + 64);
    vrg[0] = *(const bf16x8*)(Vp + (size_t)vr_ * Tc + vc_ * 8);
    vrg[1] = *(const bf16x8*)(Vp + (size_t)vr_ * Tc + vc_ * 8 + 32);
    __syncthreads();
    *(bf16x8*)&Ks[0][kidx0] = krg[0];
    *(bf16x8*)&Ks[0][kidx1] = krg[1];
    *(bf16x8*)&Vs[0][vidx0] = vrg[0];
    *(bf16x8*)&Vs[0][vidx1] = vrg[1];
    __syncthreads();

    for (int st = 0; st < nt; st++) {
      int cur = st & 1;
      int s0 = st << 6;
      if (st + 1 < nt) {
        int s1 = s0 + 64;
        krg[0] = *(const bf16x8*)(Kp + (size_t)(s1 + kr_) * Dc + kc_ * 8);
        krg[1] = *(const bf16x8*)(Kp + (size_t)(s1 + kr_) * Dc + kc_ * 8 + 64);
        vrg[0] = *(const bf16x8*)(Vp + (size_t)vr_ * Tc + s1 + vc_ * 8);
        vrg[1] = *(const bf16x8*)(Vp + (size_t)vr_ * Tc + s1 + vc_ * 8 + 32);
      }

      if (s0 <= qw0 + 31) {
        const unsigned short* Kc = &Ks[cur][0];
        const unsigned short* Vc = &Vs[cur][0];

        f32x4 S[2][4];
#pragma unroll
        for (int m = 0; m < 2; m++)
#pragma unroll
          for (int j = 0; j < 4; j++) S[m][j] = zz;
        __builtin_amdgcn_s_setprio(1);
#pragma unroll
        for (int ks = 0; ks < 4; ks++)
#pragma unroll
          for (int j = 0; j < 4; j++) {
            bf16x8 kfr = *(const bf16x8*)&Kc[(j * 16 + c) * 128 + (((ks * 4 + g) ^ (c & 7)) << 3)];
            S[0][j] = __builtin_amdgcn_mfma_f32_16x16x32_bf16(kfr, qfr[0][ks], S[0][j], 0, 0, 0);
            S[1][j] = __builtin_amdgcn_mfma_f32_16x16x32_bf16(kfr, qfr[1][ks], S[1][j], 0, 0, 0);
          }
        __builtin_amdgcn_s_setprio(0);

        if (anyz) {
#pragma unroll
          for (int j = 0; j < 4; j++)
#pragma unroll
            for (int r = 0; r < 4; r++) {
              float madd = (mp[s0 + j * 16 + g4 + r] == 0) ? -2e9f : 0.0f;
              S[0][j][r] += madd;
              S[1][j][r] += madd;
            }
        }
        if (s0 + 63 > qw0) {
#pragma unroll
          for (int j = 0; j < 4; j++) {
            int kk = s0 + j * 16 + g4;
#pragma unroll
            for (int r = 0; r < 4; r++) {
#pragma unroll
              for (int m = 0; m < 2; m++)
                if (kk + r > qw0 + m * 16 + c) S[m][j][r] = -1e30f;
            }
          }
        }

        float tmax[2];
#pragma unroll
        for (int m = 0; m < 2; m++) {
          float t0 = fmaxf(fmaxf(S[m][0][0], S[m][0][1]), fmaxf(S[m][0][2], S[m][0][3]));
          float t1 = fmaxf(fmaxf(S[m][1][0], S[m][1][1]), fmaxf(S[m][1][2], S[m][1][3]));
          float t2 = fmaxf(fmaxf(S[m][2][0], S[m][2][1]), fmaxf(S[m][2][2], S[m][2][3]));
          float t3 = fmaxf(fmaxf(S[m][3][0], S[m][3][1]), fmaxf(S[m][3][2], S[m][3][3]));
          float t = fmaxf(fmaxf(t0, t1), fmaxf(t2, t3));
          t = fmaxf(t, __shfl_xor(t, 16));
          t = fmaxf(t, __shfl_xor(t, 32));
          tmax[m] = t;
        }
        bool upd = (tmax[0] > m_r[0] + 11.0f) || (tmax[1] > m_r[1] + 11.0f);
        if (__any(upd)) {
#pragma unroll
          for (int m = 0; m < 2; m++) {
            float mn = fmaxf(m_r[m], tmax[m]);
            float al = fexp2(m_r[m] - mn);
            m_r[m] = mn;
            l_r[m] *= al;
#pragma unroll
            for (int r = 0; r < 4; r++) {
              float alr = __shfl(al, (lane & 48) | (g4 + r));
#pragma unroll
              for (int j2 = 0; j2 < 8; j2++) Oacc[m][j2][r] *= alr;
            }
          }
        }

#pragma unroll
        for (int m = 0; m < 2; m++) {
          int rowb = (m * 16 + c) * 128;
#pragma unroll
          for (int j = 0; j < 4; j++) {
            float e0 = fexp2(S[m][j][0] - m_r[m]);
            float e1 = fexp2(S[m][j][1] - m_r[m]);
            float e2 = fexp2(S[m][j][2] - m_r[m]);
            float e3 = fexp2(S[m][j][3] - m_r[m]);
            l_r[m] += (e0 + e1) + (e2 + e3);
            uint2 w;
            w.x = pkbf(e0, e1);
            w.y = pkbf(e2, e3);
            int inrow = (j * 32 + g * 8) ^ c7s;
            *(uint2*)(PwB + rowb + inrow) = w;
          }
        }

        asm volatile("s_waitcnt lgkmcnt(0)" ::: "memory");
        bf16x8 pa[2][2];
#pragma unroll
        for (int m = 0; m < 2; m++)
#pragma unroll
          for (int sk = 0; sk < 2; sk++)
            pa[m][sk] = *(const bf16x8*)(PwB + (m * 16 + c) * 128 + (((sk * 64 + g * 16)) ^ c7s));
        __builtin_amdgcn_s_setprio(1);
#pragma unroll
        for (int sk = 0; sk < 2; sk++)
#pragma unroll
          for (int j2 = 0; j2 < 8; j2++) {
            int row = j2 * 16 + c;
            bf16x8 vfr = *(const bf16x8*)&Vc[row * 64 + (((sk * 4 + g) ^ (row & 7)) << 3)];
            Oacc[0][j2] = __builtin_amdgcn_mfma_f32_16x16x32_bf16(pa[0][sk], vfr, Oacc[0][j2], 0, 0, 0);
            Oacc[1][j2] = __builtin_amdgcn_mfma_f32_16x16x32_bf16(pa[1][sk], vfr, Oacc[1][j2], 0, 0, 0);
          }
        __builtin_amdgcn_s_setprio(0);
      }

      if (st + 1 < nt) {
        int nxt = cur ^ 1;
        *(bf16x8*)&Ks[nxt][kidx0] = krg[0];
        *(bf16x8*)&Ks[nxt][kidx1] = krg[1];
        *(bf16x8*)&Vs[nxt][vidx0] = vrg[0];
        *(bf16x8*)&Vs[nxt][vidx1] = vrg[1];
      }
      __syncthreads();
    }

#pragma unroll
    for (int m = 0; m < 2; m++) {
      float lt = l_r[m];
      lt += __shfl_xor(lt, 16);
      lt += __shfl_xor(lt, 32);
      float inv = 1.0f / lt;
#pragma unroll
      for (int r = 0; r < 4; r++) {
        float invr = __shfl(inv, (lane & 48) | (g4 + r));
        int qr = qw0 + m * 16 + g4 + r;
        unsigned short* ob = O + ((size_t)(b * Tc) + qr) * HIDc + h * Dc;
#pragma unroll
        for (int j2 = 0; j2 < 8; j2++) ob[j2 * 16 + c] = f2bfb(Oacc[m][j2][r] * invr);
      }
    }
  }
}

// ---------------- host launch ----------------

extern "C" void kernel_launch(void* const* d_in, const int* in_sizes, int n_in,
                              void* d_out, int out_size, void* d_ws, size_t ws_size,
                              hipStream_t stream) {
  const float* h = (const float*)d_in[0];
  const float* cg = (const float*)d_in[1];
  const float* sg = (const float*)d_in[2];
  const float* cl = (const float*)d_in[3];
  const float* sl = (const float*)d_in[4];
  const float* Wq_a = (const float*)d_in[5];
  const float* bq_a = (const float*)d_in[6];
  const float* Wq_b = (const float*)d_in[7];
  const float* bq_b = (const float*)d_in[8];
  const float* Wkv_a = (const float*)d_in[9];
  const float* bkv_a = (const float*)d_in[10];
  const float* Wkv_b = (const float*)d_in[11];
  const float* bkv_b = (const float*)d_in[12];
  const float* qw = (const float*)d_in[13];
  const float* kvw = (const float*)d_in[14];
  const float* Wo = (const float*)d_in[15];
  const float* nl = (const float*)d_in[16];
  const float* gl = (const float*)d_in[17];
  const int* am = (const int*)d_in[18];
  float* out = (float*)d_out;
  char* ws = (char*)d_ws;

  // ws layout (bytes); Obuf at 0; A1b in freed region
  const size_t o_hB = 0;             // bf16 [8192][2048]  33554432  (Obuf)
  const size_t o_A1b = 33554432;     // f32  [8192][256]    8388608  (split-K partial)
  const size_t o_Qf = 67108864;      // bf16 [B][H][T][D]  33554432
  const size_t o_A1 = 100663296;     // f32  [8192][256]    8388608
  const size_t o_Qn = 109051904;     // bf16 [8192][128]    2097152
  const size_t o_Kvn = 111149056;    // bf16 [8192][64]     1048576
  const size_t o_Kf = 116391936;     // bf16 [8192][128]    2097152
  const size_t o_Vt = 118489088;     // bf16 [B*128][1024]  2097152
  const size_t o_W1t = 120586240;    // bf16 [256][2048]    1048576
  const size_t o_Wqbt = 121634816;   // bf16 [2048][128]     524288
  const size_t o_Wkbt = 122159104;   // bf16 [256][64]        32768
  const size_t o_Wot = 122191872;    // bf16 [2048][2048]   8388608
  const size_t o_cos = 130580480;    // f32  [65536]         262144
  const size_t o_sin = 130842624;    // f32  [65536]         262144

  unsigned short* Obuf = (unsigned short*)(ws + o_hB);
  float* A1b = (float*)(ws + o_A1b);
  unsigned short* Qf = (unsigned short*)(ws + o_Qf);
  float* A1 = (float*)(ws + o_A1);
  unsigned short* Qn = (unsigned short*)(ws + o_Qn);
  unsigned short* Kvn = (unsigned short*)(ws + o_Kvn);
  unsigned short* Kf = (unsigned short*)(ws + o_Kf);
  unsigned short* Vt = (unsigned short*)(ws + o_Vt);
  unsigned short* W1t = (unsigned short*)(ws + o_W1t);
  unsigned short* Wqbt = (unsigned short*)(ws + o_Wqbt);
  unsigned short* Wkbt = (unsigned short*)(ws + o_Wkbt);
  unsigned short* Wot = (unsigned short*)(ws + o_Wot);
  float* cosb = (float*)(ws + o_cos);
  float* sinb = (float*)(ws + o_sin);

  (void)in_sizes; (void)n_in; (void)out_size; (void)ws_size;

  // prep1: small transposes + blend + zero (W1t needed by gemm1)
  k_prep1<<<1424, 256, 0, stream>>>(Wq_a, Wkv_a, Wq_b, Wkv_b,
                                    cg, sg, cl, sl, gl,
                                    W1t, Wqbt, Wkbt, cosb, sinb);
  // gemm1 (512 blocks) + Wo transpose backfill (4096 blocks)
  k_g1wo<<<4608, 256, 0, stream>>>(h, W1t, A1, A1b, Wo, Wot);
  // split rmsnorm (sums partials)
  k_norm<<<2048, 256, 0, stream>>>(A1, A1b, bq_a, bkv_a, qw, kvw, Qn, Kvn);
  // gemm2q (1024 blocks) + gemm2kv (128 blocks) in one launch
  k_g2<<<1152, 256, 0, stream>>>(Qn, Wqbt, bq_b, Kvn, Wkbt, bkv_b,
                                 cosb, sinb, nl, Qf, Kf, Vt);
  // attention: 256 blocks (h*16 + pair*8 + b) x 512 threads (K+V staged, dbuf)
  k_attn<<<256, 512, 0, stream>>>(Qf, Kf, Vt, am, Obuf);
  // GEMM3: 256^2 BK=64 2-slice counted-vmcnt pipeline -> fp32 out
  k_gemm3<<<256, 512, 0, stream>>>(Obuf, Wot, out);
}